// Round 1
// baseline (4697.873 us; speedup 1.0000x reference)
//
#include <hip/hip_runtime.h>
#include <cstddef>
#include <cstdint>

#define TPB 256

template<int ACT>
__device__ __forceinline__ float act_f(float v) {
  if (ACT == 1) return v >= 0.f ? v : 0.1f * v;          // lrelu
  if (ACT == 2) return 1.f / (1.f + expf(-v));           // sigmoid
  return v;
}

// ---------------------------------------------------------------------------
// 3x3 conv, stride 1, pad 1. Input optionally split across two tensors
// (channel concat): in1 has c1 channels, then in2 has c2. Weights [Cout][Cin][3][3].
// Block: 256 threads -> 16x16 spatial tile x 16 output channels.
// Thread: 4 px along x, 4 co. Weights broadcast from LDS as float4 (wave-uniform),
// input window 3x6 from LDS tile.
// ---------------------------------------------------------------------------
template<int ACT>
__global__ __launch_bounds__(TPB)
void k_conv3x3(const float* __restrict__ in1, int c1,
               const float* __restrict__ in2, int c2,
               const float* __restrict__ wgt, const float* __restrict__ bias,
               float* __restrict__ out, int Cout, int Hh, int Ww)
{
  __shared__ __align__(16) float s_in[16][18][20];
  __shared__ __align__(16) float s_w[16][9][16];
  const int Cin = c1 + c2;
  const int b   = blockIdx.z;
  const int cob = blockIdx.y << 4;
  const int tilesX = Ww >> 4;
  const int ty0 = (blockIdx.x / tilesX) << 4;
  const int tx0 = (blockIdx.x % tilesX) << 4;
  const int tid = threadIdx.x;
  const int xg  = (tid & 3) << 2;          // x offset within tile: 0,4,8,12
  const int yy  = (tid >> 2) & 15;         // row within tile
  const int cg  = ((tid >> 6) & 3) << 2;   // co offset within chunk: 0,4,8,12 (wave-uniform)
  const int HW  = Hh * Ww;

  float acc[4][4];
#pragma unroll
  for (int p = 0; p < 4; ++p)
#pragma unroll
    for (int j = 0; j < 4; ++j) acc[p][j] = 0.f;

  for (int cib = 0; cib < Cin; cib += 16) {
    // stage 18x18x16ci input tile (zero-padded at borders)
    for (int idx = tid; idx < 16 * 18 * 18; idx += TPB) {
      int ci = idx / 324;
      int rem = idx - ci * 324;
      int r = rem / 18, c = rem - r * 18;
      int gy = ty0 - 1 + r, gx = tx0 - 1 + c;
      float v = 0.f;
      if ((unsigned)gy < (unsigned)Hh && (unsigned)gx < (unsigned)Ww) {
        int gc = cib + ci;
        const float* src = (gc < c1)
            ? in1 + ((size_t)b * c1 + gc) * HW
            : in2 + ((size_t)b * c2 + (gc - c1)) * HW;
        v = src[gy * Ww + gx];
      }
      s_in[ci][r][c] = v;
    }
    // stage weights [ci][tap][co16]
    for (int idx = tid; idx < 16 * 9 * 16; idx += TPB) {
      int ci = idx / 144;
      int rem = idx - ci * 144;
      int tap = rem / 16, col = rem - tap * 16;
      int co = cob + col;
      s_w[ci][tap][col] = (co < Cout)
          ? wgt[((size_t)co * Cin + cib + ci) * 9 + tap] : 0.f;
    }
    __syncthreads();
#pragma unroll 1
    for (int ci = 0; ci < 16; ++ci) {
      float win[3][6];
#pragma unroll
      for (int r = 0; r < 3; ++r)
#pragma unroll
        for (int c = 0; c < 6; ++c) win[r][c] = s_in[ci][yy + r][xg + c];
#pragma unroll
      for (int ky = 0; ky < 3; ++ky)
#pragma unroll
        for (int kx = 0; kx < 3; ++kx) {
          const float4 wv = *(const float4*)&s_w[ci][ky * 3 + kx][cg];
#pragma unroll
          for (int p = 0; p < 4; ++p) {
            const float v = win[ky][kx + p];
            acc[p][0] = fmaf(v, wv.x, acc[p][0]);
            acc[p][1] = fmaf(v, wv.y, acc[p][1]);
            acc[p][2] = fmaf(v, wv.z, acc[p][2]);
            acc[p][3] = fmaf(v, wv.w, acc[p][3]);
          }
        }
    }
    __syncthreads();
  }
  const int oy = ty0 + yy;
#pragma unroll
  for (int j = 0; j < 4; ++j) {
    const int co = cob + cg + j;
    if (co < Cout) {
      const float bv = bias[co];
      float* dst = out + ((size_t)b * Cout + co) * HW + oy * Ww + tx0 + xg;
#pragma unroll
      for (int p = 0; p < 4; ++p) dst[p] = act_f<ACT>(acc[p][j] + bv);
    }
  }
}

// ---------------------------------------------------------------------------
// Modulated deformable 3x3 conv, stride 1 pad 1, G=8 groups, C=64 (Cg=8, Co/g=8).
// off: the 216-ch "om" tensor; offset channel = g*18 + 2k + d.
// mask: maskC channels per batch, channel maskBase + g*9 + k; SIGM applies sigmoid.
// Thread: one (pixel, group) -> 8 output channels.
// ---------------------------------------------------------------------------
template<int SIGM, int ACT>
__global__ __launch_bounds__(TPB)
void k_dconv(const float* __restrict__ x,
             const float* __restrict__ off,
             const float* __restrict__ mask, int maskC, int maskBase,
             const float* __restrict__ wgt, const float* __restrict__ bias,
             float* __restrict__ out, int Hh, int Ww)
{
  __shared__ __align__(16) float s_w[8 * 9 * 8 * 8];   // [g][k][c][o]
  for (int i = threadIdx.x; i < 4608; i += TPB) {
    int o = i & 7, c = (i >> 3) & 7, k = (i >> 6) % 9, g = i / 576;
    s_w[i] = wgt[(((size_t)(g * 8 + o)) * 8 + c) * 9 + k];
  }
  __syncthreads();
  const int b = blockIdx.y;
  const int g = threadIdx.x >> 5;
  const int p = blockIdx.x * 32 + (threadIdx.x & 31);
  const int HW = Hh * Ww;
  const int y = p / Ww, xx = p - y * Ww;
  const float* xb  = x   + ((size_t)b * 64 + g * 8) * HW;
  const float* opb = off + (size_t)b * 216 * HW + (size_t)g * 18 * HW + p;
  const float* mb  = mask + (size_t)b * maskC * HW + (size_t)(maskBase + g * 9) * HW + p;
  float acc[8];
#pragma unroll
  for (int o = 0; o < 8; ++o) acc[o] = bias[g * 8 + o];
#pragma unroll 1
  for (int k = 0; k < 9; ++k) {
    const float oy = opb[(size_t)(2 * k) * HW];
    const float ox = opb[(size_t)(2 * k + 1) * HW];
    float m = mb[(size_t)k * HW];
    if (SIGM) m = 1.f / (1.f + expf(-m));
    const float py = (float)(y + k / 3 - 1) + oy;
    const float px = (float)(xx + k % 3 - 1) + ox;
    const float y0f = floorf(py), x0f = floorf(px);
    const float fy = py - y0f, fx = px - x0f;
    const int y0 = (int)y0f, x0 = (int)x0f;
    const int y1 = y0 + 1, x1 = x0 + 1;
    const float vy0 = (y0 >= 0 && y0 < Hh) ? 1.f : 0.f;
    const float vy1 = (y1 >= 0 && y1 < Hh) ? 1.f : 0.f;
    const float vx0 = (x0 >= 0 && x0 < Ww) ? 1.f : 0.f;
    const float vx1 = (x1 >= 0 && x1 < Ww) ? 1.f : 0.f;
    const int cy0 = min(max(y0, 0), Hh - 1), cy1 = min(max(y1, 0), Hh - 1);
    const int cx0 = min(max(x0, 0), Ww - 1), cx1 = min(max(x1, 0), Ww - 1);
    const float w00 = (1.f - fy) * (1.f - fx) * vy0 * vx0 * m;
    const float w01 = (1.f - fy) * fx * vy0 * vx1 * m;
    const float w10 = fy * (1.f - fx) * vy1 * vx0 * m;
    const float w11 = fy * fx * vy1 * vx1 * m;
    const int i00 = cy0 * Ww + cx0, i01 = cy0 * Ww + cx1;
    const int i10 = cy1 * Ww + cx0, i11 = cy1 * Ww + cx1;
    const float* wk = &s_w[(g * 9 + k) * 64];
#pragma unroll
    for (int c = 0; c < 8; ++c) {
      const float* pl = xb + (size_t)c * HW;
      const float s = w00 * pl[i00] + w01 * pl[i01] + w10 * pl[i10] + w11 * pl[i11];
      const float4 wv0 = *(const float4*)&wk[c * 8];
      const float4 wv1 = *(const float4*)&wk[c * 8 + 4];
      acc[0] = fmaf(s, wv0.x, acc[0]); acc[1] = fmaf(s, wv0.y, acc[1]);
      acc[2] = fmaf(s, wv0.z, acc[2]); acc[3] = fmaf(s, wv0.w, acc[3]);
      acc[4] = fmaf(s, wv1.x, acc[4]); acc[5] = fmaf(s, wv1.y, acc[5]);
      acc[6] = fmaf(s, wv1.z, acc[6]); acc[7] = fmaf(s, wv1.w, acc[7]);
    }
  }
  float* po = out + ((size_t)b * 64 + g * 8) * HW + p;
#pragma unroll
  for (int o = 0; o < 8; ++o) po[(size_t)o * HW] = act_f<ACT>(acc[o]);
}

// ---------------------------------------------------------------------------
// Bilinear 2x upsample (jax.image.resize 'bilinear', half-pixel, edge-clamped)
// ---------------------------------------------------------------------------
__global__ void k_up2(const float* __restrict__ in, float* __restrict__ out,
                      int planes, int h, int w)
{
  const int ow = 2 * w, oh = 2 * h;
  const int total = planes * oh * ow;
  int idx = blockIdx.x * TPB + threadIdx.x;
  if (idx >= total) return;
  const int pl = idx / (oh * ow);
  const int rem = idx - pl * (oh * ow);
  const int oyj = rem / ow, oxj = rem - oyj * ow;
  int iy0, iy1, ix0, ix1; float wy0, wy1, wx0, wx1;
  if (oyj & 1) { iy0 = oyj >> 1; iy1 = min(iy0 + 1, h - 1); wy0 = 0.75f; wy1 = 0.25f; }
  else         { iy1 = oyj >> 1; iy0 = max(iy1 - 1, 0);     wy0 = 0.25f; wy1 = 0.75f; }
  if (oxj & 1) { ix0 = oxj >> 1; ix1 = min(ix0 + 1, w - 1); wx0 = 0.75f; wx1 = 0.25f; }
  else         { ix1 = oxj >> 1; ix0 = max(ix1 - 1, 0);     wx0 = 0.25f; wx1 = 0.75f; }
  const float* pp = in + (size_t)pl * h * w;
  out[idx] = wy0 * (wx0 * pp[iy0 * w + ix0] + wx1 * pp[iy0 * w + ix1])
           + wy1 * (wx0 * pp[iy1 * w + ix0] + wx1 * pp[iy1 * w + ix1]);
}

// ---------------------------------------------------------------------------
// host-side launch helpers (B = 2 fixed)
// ---------------------------------------------------------------------------
static void conv3(hipStream_t st, const float* in1, int c1, const float* in2, int c2,
                  const float* w, const float* b, float* out, int Cout, int h, int wd, int act)
{
  dim3 grid((h / 16) * (wd / 16), (Cout + 15) / 16, 2);
  if (act == 0)      k_conv3x3<0><<<grid, TPB, 0, st>>>(in1, c1, in2, c2, w, b, out, Cout, h, wd);
  else if (act == 1) k_conv3x3<1><<<grid, TPB, 0, st>>>(in1, c1, in2, c2, w, b, out, Cout, h, wd);
  else               k_conv3x3<2><<<grid, TPB, 0, st>>>(in1, c1, in2, c2, w, b, out, Cout, h, wd);
}

static void dconv(hipStream_t st, const float* x, const float* om, const float* mask,
                  int maskC, int maskBase, const float* w, const float* b, float* out,
                  int h, int wd, int sigm, int act)
{
  dim3 grid((h * wd) / 32, 2);
  if (sigm) {
    if (act) k_dconv<1,1><<<grid, TPB, 0, st>>>(x, om, mask, maskC, maskBase, w, b, out, h, wd);
    else     k_dconv<1,0><<<grid, TPB, 0, st>>>(x, om, mask, maskC, maskBase, w, b, out, h, wd);
  } else     k_dconv<0,0><<<grid, TPB, 0, st>>>(x, om, mask, maskC, maskBase, w, b, out, h, wd);
}

static void up2(hipStream_t st, const float* in, float* out, int h, int w)
{
  int total = 128 * 4 * h * w;  // B*C = 128 planes, out (2h)x(2w)
  k_up2<<<(total + TPB - 1) / TPB, TPB, 0, st>>>(in, out, 128, h, w);
}

extern "C" void kernel_launch(void* const* d_in, const int* in_sizes, int n_in,
                              void* d_out, int out_size, void* d_ws, size_t ws_size,
                              hipStream_t stream)
{
  const float* const* in = (const float* const*)d_in;
  const float* nrf0 = in[0]; const float* rf0 = in[1]; const float* swf0 = in[2];
  const float* nrf1 = in[3]; const float* rf1 = in[4]; const float* swf1 = in[5];
  const float* nrf2 = in[6]; const float* rf2 = in[7]; const float* swf2 = in[8];

  float* ws = (float*)d_ws;
  const size_t L0 = (size_t)2 * 64 * 192 * 192;    // 4,718,592 floats
  float* A   = ws;
  float* Bb  = A   + L0;
  float* U   = Bb  + L0;
  float* OM  = U   + L0;                           // 2*216*192*192
  float* EM  = OM  + (size_t)2 * 216 * 192 * 192;  // 2*72*192*192
  float* of1 = EM  + (size_t)2 * 72 * 192 * 192;
  float* dn1 = of1 + L0 / 4;
  float* of2 = dn1 + L0 / 4;
  float* dn2 = of2 + L0 / 16;

  float* dout = (float*)d_out;
  float* out0 = dout;
  float* sh0  = dout + L0;
  float* sh1  = sh0  + L0;
  float* sh2  = sh1  + L0 / 4;

  // ----- level 2 (48x48): params base 33 -----
  const int h2 = 48;
  conv3(stream, nrf2, 64, rf2, 64,  in[33], in[34], A,   64,  h2, h2, 1);  // ocf2, lrelu
  conv3(stream, A,    64, 0,   0,   in[35], in[36], of2, 64,  h2, h2, 1);  // ocl2 -> of2
  conv3(stream, swf2, 64, 0,   0,   in[37], in[38], OM,  216, h2, h2, 0);  // so2_com -> om
  conv3(stream, of2,  64, swf2, 64, in[39], in[40], Bb,  64,  h2, h2, 1);  // so2_em1
  conv3(stream, Bb,   64, 0,   0,   in[41], in[42], EM,  72,  h2, h2, 2);  // so2_em2, sigmoid
  dconv(stream, of2,  OM, EM,  72, 0,   in[43], in[44], sh2, h2, h2, 0, 0); // ds2 -> shares[2]
  dconv(stream, nrf2, OM, OM, 216, 144, in[43], in[44], dn2, h2, h2, 1, 1); // xd2 + lrelu -> dn2

  // ----- level 1 (96x96): params base 21; occ1=49/50, fcc1=51/52 -----
  const int h1 = 96;
  up2(stream, of2, U, h2, h2);                                             // U = up2(of2)
  conv3(stream, nrf1, 64, rf1, 64,  in[21], in[22], A,   64,  h1, h1, 1);  // ocf1
  conv3(stream, A,    64, U,   64,  in[49], in[50], Bb,  64,  h1, h1, 1);  // occ1
  conv3(stream, Bb,   64, 0,   0,   in[23], in[24], of1, 64,  h1, h1, 1);  // ocl1 -> of1
  conv3(stream, swf1, 64, 0,   0,   in[25], in[26], OM,  216, h1, h1, 0);  // so1_com
  conv3(stream, of1,  64, swf1, 64, in[27], in[28], A,   64,  h1, h1, 1);  // so1_em1
  conv3(stream, A,    64, 0,   0,   in[29], in[30], EM,  72,  h1, h1, 2);  // so1_em2, sigmoid
  dconv(stream, of1,  OM, EM,  72, 0,   in[31], in[32], sh1, h1, h1, 0, 0); // ds1 -> shares[1]
  dconv(stream, nrf1, OM, OM, 216, 144, in[31], in[32], A,   h1, h1, 1, 0); // xd1 -> A
  up2(stream, dn2, U, h2, h2);                                             // U = up2(dn2)
  conv3(stream, A,    64, U,   64,  in[51], in[52], dn1, 64,  h1, h1, 1);  // fcc1 + lrelu -> dn1

  // ----- level 0 (192x192): params base 9; occ0=45/46, fcc0=47/48, cas=53..60 -----
  const int h0 = 192;
  up2(stream, of1, U, h1, h1);                                             // U = up2(of1)
  conv3(stream, nrf0, 64, rf0, 64,  in[9],  in[10], A,   64,  h0, h0, 1);  // ocf0
  conv3(stream, A,    64, U,   64,  in[45], in[46], Bb,  64,  h0, h0, 1);  // occ0
  conv3(stream, Bb,   64, 0,   0,   in[11], in[12], A,   64,  h0, h0, 1);  // ocl0 -> of0 (A)
  conv3(stream, swf0, 64, 0,   0,   in[13], in[14], OM,  216, h0, h0, 0);  // so0_com
  conv3(stream, A,    64, swf0, 64, in[15], in[16], Bb,  64,  h0, h0, 1);  // so0_em1
  conv3(stream, Bb,   64, 0,   0,   in[17], in[18], EM,  72,  h0, h0, 2);  // so0_em2, sigmoid
  dconv(stream, A,    OM, EM,  72, 0,   in[19], in[20], sh0, h0, h0, 0, 0); // ds0 -> shares[0]
  dconv(stream, nrf0, OM, OM, 216, 144, in[19], in[20], Bb,  h0, h0, 1, 0); // xd0 -> Bb
  up2(stream, dn1, U, h1, h1);                                             // U = up2(dn1)
  conv3(stream, Bb,   64, U,   64,  in[47], in[48], A,   64,  h0, h0, 0);  // fcc0 (no act) -> dn0 (A)
  conv3(stream, A,    64, rf0, 64,  in[53], in[54], Bb,  64,  h0, h0, 1);  // cas1
  conv3(stream, Bb,   64, 0,   0,   in[55], in[56], U,   64,  h0, h0, 1);  // cas2 -> U
  conv3(stream, U,    64, 0,   0,   in[57], in[58], OM,  216, h0, h0, 0);  // cas_com
  dconv(stream, A,    OM, OM, 216, 144, in[59], in[60], out0, h0, h0, 1, 1); // final dconv + lrelu
}

// Round 2
// 1981.957 us; speedup vs baseline: 2.3703x; 2.3703x over previous
//
#include <hip/hip_runtime.h>
#include <cstddef>
#include <cstdint>

#define TPB 256

typedef unsigned int u32;
typedef unsigned short u16;
typedef __bf16 bf16x8 __attribute__((ext_vector_type(8)));
typedef float f32x4 __attribute__((ext_vector_type(4)));

template<int ACT>
__device__ __forceinline__ float act_f(float v) {
  if (ACT == 1) return v >= 0.f ? v : 0.1f * v;          // lrelu
  if (ACT == 2) return 1.f / (1.f + expf(-v));           // sigmoid
  return v;
}

__device__ __forceinline__ u16 f2bf(float f) {           // fp32 -> bf16 RNE
  u32 u = __float_as_uint(f);
  u32 r = u + 0x7FFFu + ((u >> 16) & 1u);
  return (u16)(r >> 16);
}
__device__ __forceinline__ float bf2f(u16 h) {
  return __uint_as_float(((u32)h) << 16);
}

// ---------------------------------------------------------------------------
// Weight prep: fp32 [Cout][Cin][3][3] -> bf16 hi/lo planes laid out as
// [kc][tap][plane][co (padded to Coutpad)][40]  (k padded 32->40 for banks)
// ---------------------------------------------------------------------------
__global__ void k_wprep(const float* __restrict__ w, u16* __restrict__ dst,
                        int Cin, int Cout, int Coutpad, int total)
{
  int idx = blockIdx.x * TPB + threadIdx.x;
  if (idx >= total) return;
  int kk = idx % 40; int t = idx / 40;
  int co = t % Coutpad; t /= Coutpad;
  int plane = t & 1; t >>= 1;
  int tap = t % 9; int kc = t / 9;
  u16 v = 0;
  if (kk < 32 && co < Cout) {
    float w0 = w[((size_t)co * Cin + kc * 32 + kk) * 9 + tap];
    u16 hi = f2bf(w0);
    v = plane ? f2bf(w0 - bf2f(hi)) : hi;
  }
  dst[idx] = v;
}

// ---------------------------------------------------------------------------
// 3x3 conv via MFMA bf16 3-pass split. Block: 16x16 px tile x 64 co, 4 waves.
// Wave w: rows w*4..w*4+3; per wave 4 px-groups x 4 co-tiles, K-chunk 32 ci.
// Act LDS: [18 y][18 x][72: hi32|lo32|pad8] bf16 (pixel stride 144B -> 2-way free)
// W   LDS: [3 kx][2 plane][64 co][40 k] bf16 (co stride 80B -> conflict-free)
// ---------------------------------------------------------------------------
template<int ACT>
__global__ __launch_bounds__(TPB, 2)
void k_conv_mfma(const float* __restrict__ in1, int c1,
                 const float* __restrict__ in2, int c2,
                 const u16* __restrict__ wbuf, const float* __restrict__ bias,
                 float* __restrict__ out, int Cout, int Coutpad, int Hh, int Ww)
{
  __shared__ __align__(16) u16 s_act[18 * 18 * 72];
  __shared__ __align__(16) u16 s_w[3 * 2 * 64 * 40];
  const int Cin = c1 + c2;
  const int b   = blockIdx.z;
  const int cb  = blockIdx.y << 6;
  const int xt  = Ww >> 4;
  const int by0 = (blockIdx.x / xt) << 4;
  const int bx0 = (blockIdx.x % xt) << 4;
  const int tid = threadIdx.x;
  const int lx = tid & 15, slot = (tid >> 4) & 3, wv = tid >> 6;
  const int HW = Hh * Ww;

  f32x4 acc[4][4];
#pragma unroll
  for (int i = 0; i < 4; ++i)
#pragma unroll
    for (int j = 0; j < 4; ++j) acc[i][j] = (f32x4){0.f, 0.f, 0.f, 0.f};

#pragma unroll 1
  for (int kc = 0; kc < (Cin >> 5); ++kc) {
    __syncthreads();
    // ---- stage activations: 18x18 positions x 32 ci, fp32 -> bf16 hi/lo ----
    {
      const int cbase = kc << 5;
      const float* sp = (cbase < c1) ? in1 + ((size_t)b * c1 + cbase) * HW
                                     : in2 + ((size_t)b * c2 + (cbase - c1)) * HW;
#pragma unroll 1
      for (int u = tid; u < 324; u += TPB) {
        int y = u / 18, x = u - y * 18;
        int gy = by0 - 1 + y, gx = bx0 - 1 + x;
        bool inb = ((unsigned)gy < (unsigned)Hh) & ((unsigned)gx < (unsigned)Ww);
        const float msk = inb ? 1.f : 0.f;
        const size_t poff = inb ? ((size_t)gy * Ww + gx) : 0;
        const float* s0 = sp + poff;
        u16* dp = &s_act[(y * 18 + x) * 72];
#pragma unroll
        for (int c8 = 0; c8 < 4; ++c8) {
          u32 hb[4], lb[4];
#pragma unroll
          for (int j = 0; j < 4; ++j) {
            float a0 = s0[(size_t)(c8 * 8 + 2 * j) * HW] * msk;
            float a1 = s0[(size_t)(c8 * 8 + 2 * j + 1) * HW] * msk;
            u16 h0 = f2bf(a0), h1 = f2bf(a1);
            hb[j] = (u32)h0 | ((u32)h1 << 16);
            lb[j] = (u32)f2bf(a0 - bf2f(h0)) | ((u32)f2bf(a1 - bf2f(h1)) << 16);
          }
          *(uint4*)&dp[c8 * 8]      = make_uint4(hb[0], hb[1], hb[2], hb[3]);
          *(uint4*)&dp[32 + c8 * 8] = make_uint4(lb[0], lb[1], lb[2], lb[3]);
        }
      }
    }
#pragma unroll 1
    for (int ky = 0; ky < 3; ++ky) {
      __syncthreads();
      // ---- stage weights: 3 taps x 2 planes x 64 co x 40 k ----
      {
        const size_t segstride = (size_t)Coutpad * 40;
        const size_t tb = (size_t)((kc * 9 + ky * 3) * 2) * segstride + (size_t)cb * 40;
#pragma unroll 1
        for (int i = tid; i < 1920; i += TPB) {
          int seg = i / 320, j = i - seg * 320;
          const uint4 v = *(const uint4*)&wbuf[tb + (size_t)seg * segstride + j * 8];
          *(uint4*)&s_w[seg * 2560 + j * 8] = v;
        }
      }
      __syncthreads();
#pragma unroll
      for (int kx = 0; kx < 3; ++kx) {
        bf16x8 Af[4][2], Bf[4][2];
#pragma unroll
        for (int ct = 0; ct < 4; ++ct)
#pragma unroll
          for (int p = 0; p < 2; ++p)
            Af[ct][p] = *(const bf16x8*)&s_w[((kx * 2 + p) * 64 + ct * 16 + lx) * 40 + slot * 8];
#pragma unroll
        for (int pg = 0; pg < 4; ++pg)
#pragma unroll
          for (int p = 0; p < 2; ++p)
            Bf[pg][p] = *(const bf16x8*)&s_act[((wv * 4 + pg + ky) * 18 + lx + kx) * 72 + p * 32 + slot * 8];
#pragma unroll
        for (int ct = 0; ct < 4; ++ct)
#pragma unroll
          for (int pg = 0; pg < 4; ++pg) {
            acc[ct][pg] = __builtin_amdgcn_mfma_f32_16x16x32_bf16(Af[ct][0], Bf[pg][0], acc[ct][pg], 0, 0, 0);
            acc[ct][pg] = __builtin_amdgcn_mfma_f32_16x16x32_bf16(Af[ct][1], Bf[pg][0], acc[ct][pg], 0, 0, 0);
            acc[ct][pg] = __builtin_amdgcn_mfma_f32_16x16x32_bf16(Af[ct][0], Bf[pg][1], acc[ct][pg], 0, 0, 0);
          }
      }
    }
  }
  // ---- epilogue: D row = co-in-tile = slot*4+r, col = pixel = lx ----
  const int ox = bx0 + lx;
#pragma unroll
  for (int ct = 0; ct < 4; ++ct) {
    const int co0 = cb + ct * 16 + slot * 4;
#pragma unroll
    for (int r = 0; r < 4; ++r) {
      const int co = co0 + r;
      if (co < Cout) {
        const float bv = bias[co];
        float* op = out + ((size_t)b * Cout + co) * HW + (size_t)(by0 + wv * 4) * Ww + ox;
#pragma unroll
        for (int pg = 0; pg < 4; ++pg)
          op[pg * Ww] = act_f<ACT>(acc[ct][pg][r] + bv);
      }
    }
  }
}

// ---------------------------------------------------------------------------
// Modulated deformable 3x3 conv (unchanged from round 1)
// ---------------------------------------------------------------------------
template<int SIGM, int ACT>
__global__ __launch_bounds__(TPB)
void k_dconv(const float* __restrict__ x,
             const float* __restrict__ off,
             const float* __restrict__ mask, int maskC, int maskBase,
             const float* __restrict__ wgt, const float* __restrict__ bias,
             float* __restrict__ out, int Hh, int Ww)
{
  __shared__ __align__(16) float s_w[8 * 9 * 8 * 8];   // [g][k][c][o]
  for (int i = threadIdx.x; i < 4608; i += TPB) {
    int o = i & 7, c = (i >> 3) & 7, k = (i >> 6) % 9, g = i / 576;
    s_w[i] = wgt[(((size_t)(g * 8 + o)) * 8 + c) * 9 + k];
  }
  __syncthreads();
  const int b = blockIdx.y;
  const int g = threadIdx.x >> 5;
  const int p = blockIdx.x * 32 + (threadIdx.x & 31);
  const int HW = Hh * Ww;
  const int y = p / Ww, xx = p - y * Ww;
  const float* xb  = x   + ((size_t)b * 64 + g * 8) * HW;
  const float* opb = off + (size_t)b * 216 * HW + (size_t)g * 18 * HW + p;
  const float* mb  = mask + (size_t)b * maskC * HW + (size_t)(maskBase + g * 9) * HW + p;
  float acc[8];
#pragma unroll
  for (int o = 0; o < 8; ++o) acc[o] = bias[g * 8 + o];
#pragma unroll 1
  for (int k = 0; k < 9; ++k) {
    const float oy = opb[(size_t)(2 * k) * HW];
    const float ox = opb[(size_t)(2 * k + 1) * HW];
    float m = mb[(size_t)k * HW];
    if (SIGM) m = 1.f / (1.f + expf(-m));
    const float py = (float)(y + k / 3 - 1) + oy;
    const float px = (float)(xx + k % 3 - 1) + ox;
    const float y0f = floorf(py), x0f = floorf(px);
    const float fy = py - y0f, fx = px - x0f;
    const int y0 = (int)y0f, x0 = (int)x0f;
    const int y1 = y0 + 1, x1 = x0 + 1;
    const float vy0 = (y0 >= 0 && y0 < Hh) ? 1.f : 0.f;
    const float vy1 = (y1 >= 0 && y1 < Hh) ? 1.f : 0.f;
    const float vx0 = (x0 >= 0 && x0 < Ww) ? 1.f : 0.f;
    const float vx1 = (x1 >= 0 && x1 < Ww) ? 1.f : 0.f;
    const int cy0 = min(max(y0, 0), Hh - 1), cy1 = min(max(y1, 0), Hh - 1);
    const int cx0 = min(max(x0, 0), Ww - 1), cx1 = min(max(x1, 0), Ww - 1);
    const float w00 = (1.f - fy) * (1.f - fx) * vy0 * vx0 * m;
    const float w01 = (1.f - fy) * fx * vy0 * vx1 * m;
    const float w10 = fy * (1.f - fx) * vy1 * vx0 * m;
    const float w11 = fy * fx * vy1 * vx1 * m;
    const int i00 = cy0 * Ww + cx0, i01 = cy0 * Ww + cx1;
    const int i10 = cy1 * Ww + cx0, i11 = cy1 * Ww + cx1;
    const float* wk = &s_w[(g * 9 + k) * 64];
#pragma unroll
    for (int c = 0; c < 8; ++c) {
      const float* pl = xb + (size_t)c * HW;
      const float s = w00 * pl[i00] + w01 * pl[i01] + w10 * pl[i10] + w11 * pl[i11];
      const float4 wv0 = *(const float4*)&wk[c * 8];
      const float4 wv1 = *(const float4*)&wk[c * 8 + 4];
      acc[0] = fmaf(s, wv0.x, acc[0]); acc[1] = fmaf(s, wv0.y, acc[1]);
      acc[2] = fmaf(s, wv0.z, acc[2]); acc[3] = fmaf(s, wv0.w, acc[3]);
      acc[4] = fmaf(s, wv1.x, acc[4]); acc[5] = fmaf(s, wv1.y, acc[5]);
      acc[6] = fmaf(s, wv1.z, acc[6]); acc[7] = fmaf(s, wv1.w, acc[7]);
    }
  }
  float* po = out + ((size_t)b * 64 + g * 8) * HW + p;
#pragma unroll
  for (int o = 0; o < 8; ++o) po[(size_t)o * HW] = act_f<ACT>(acc[o]);
}

// ---------------------------------------------------------------------------
// Bilinear 2x upsample (unchanged)
// ---------------------------------------------------------------------------
__global__ void k_up2(const float* __restrict__ in, float* __restrict__ out,
                      int planes, int h, int w)
{
  const int ow = 2 * w, oh = 2 * h;
  const int total = planes * oh * ow;
  int idx = blockIdx.x * TPB + threadIdx.x;
  if (idx >= total) return;
  const int pl = idx / (oh * ow);
  const int rem = idx - pl * (oh * ow);
  const int oyj = rem / ow, oxj = rem - oyj * ow;
  int iy0, iy1, ix0, ix1; float wy0, wy1, wx0, wx1;
  if (oyj & 1) { iy0 = oyj >> 1; iy1 = min(iy0 + 1, h - 1); wy0 = 0.75f; wy1 = 0.25f; }
  else         { iy1 = oyj >> 1; iy0 = max(iy1 - 1, 0);     wy0 = 0.25f; wy1 = 0.75f; }
  if (oxj & 1) { ix0 = oxj >> 1; ix1 = min(ix0 + 1, w - 1); wx0 = 0.75f; wx1 = 0.25f; }
  else         { ix1 = oxj >> 1; ix0 = max(ix1 - 1, 0);     wx0 = 0.25f; wx1 = 0.75f; }
  const float* pp = in + (size_t)pl * h * w;
  out[idx] = wy0 * (wx0 * pp[iy0 * w + ix0] + wx1 * pp[iy0 * w + ix1])
           + wy1 * (wx0 * pp[iy1 * w + ix0] + wx1 * pp[iy1 * w + ix1]);
}

// ---------------------------------------------------------------------------
// host-side helpers (B = 2 fixed)
// ---------------------------------------------------------------------------
static void conv3(hipStream_t st, const float* in1, int c1, const float* in2, int c2,
                  const u16* wbuf, const float* b, float* out, int Cout, int h, int wd, int act)
{
  int cocols = (Cout + 63) / 64, Coutpad = cocols * 64;
  dim3 grid((h / 16) * (wd / 16), cocols, 2);
  if (act == 0)      k_conv_mfma<0><<<grid, TPB, 0, st>>>(in1, c1, in2, c2, wbuf, b, out, Cout, Coutpad, h, wd);
  else if (act == 1) k_conv_mfma<1><<<grid, TPB, 0, st>>>(in1, c1, in2, c2, wbuf, b, out, Cout, Coutpad, h, wd);
  else               k_conv_mfma<2><<<grid, TPB, 0, st>>>(in1, c1, in2, c2, wbuf, b, out, Cout, Coutpad, h, wd);
}

static void dconv(hipStream_t st, const float* x, const float* om, const float* mask,
                  int maskC, int maskBase, const float* w, const float* b, float* out,
                  int h, int wd, int sigm, int act)
{
  dim3 grid((h * wd) / 32, 2);
  if (sigm) {
    if (act) k_dconv<1,1><<<grid, TPB, 0, st>>>(x, om, mask, maskC, maskBase, w, b, out, h, wd);
    else     k_dconv<1,0><<<grid, TPB, 0, st>>>(x, om, mask, maskC, maskBase, w, b, out, h, wd);
  } else     k_dconv<0,0><<<grid, TPB, 0, st>>>(x, om, mask, maskC, maskBase, w, b, out, h, wd);
}

static void up2(hipStream_t st, const float* in, float* out, int h, int w)
{
  int total = 128 * 4 * h * w;
  k_up2<<<(total + TPB - 1) / TPB, TPB, 0, st>>>(in, out, 128, h, w);
}

extern "C" void kernel_launch(void* const* d_in, const int* in_sizes, int n_in,
                              void* d_out, int out_size, void* d_ws, size_t ws_size,
                              hipStream_t stream)
{
  const float* const* in = (const float* const*)d_in;
  const float* nrf0 = in[0]; const float* rf0 = in[1]; const float* swf0 = in[2];
  const float* nrf1 = in[3]; const float* rf1 = in[4]; const float* swf1 = in[5];
  const float* nrf2 = in[6]; const float* rf2 = in[7]; const float* swf2 = in[8];

  float* ws = (float*)d_ws;
  const size_t L0 = (size_t)2 * 64 * 192 * 192;    // 4,718,592 floats
  float* A   = ws;
  float* Bb  = A   + L0;
  float* U   = Bb  + L0;
  float* OM  = U   + L0;                           // 2*216*192*192
  float* EM  = OM  + (size_t)2 * 216 * 192 * 192;  // 2*72*192*192
  float* of1 = EM  + (size_t)2 * 72 * 192 * 192;
  float* dn1 = of1 + L0 / 4;
  float* of2 = dn1 + L0 / 4;
  float* dn2 = of2 + L0 / 16;
  u16*   wp  = (u16*)(dn2 + L0 / 16);              // bf16 weight buffers

  float* dout = (float*)d_out;
  float* out0 = dout;
  float* sh0  = dout + L0;
  float* sh1  = sh0  + L0;
  float* sh2  = sh1  + L0 / 4;

  // ---- pre-split all conv weights into bf16 hi/lo, MFMA-friendly layout ----
  auto prep = [&](const float* w, int Cin, int Cout) -> u16* {
    int cocols = (Cout + 63) / 64, Coutpad = cocols * 64;
    int total = (Cin / 32) * 9 * 2 * Coutpad * 40;
    u16* ret = wp;
    k_wprep<<<(total + TPB - 1) / TPB, TPB, 0, stream>>>(w, ret, Cin, Cout, Coutpad, total);
    wp += total;
    return ret;
  };
  u16* w_ocf0  = prep(in[9],  128, 64);
  u16* w_ocl0  = prep(in[11],  64, 64);
  u16* w_com0  = prep(in[13],  64, 216);
  u16* w_em10  = prep(in[15], 128, 64);
  u16* w_em20  = prep(in[17],  64, 72);
  u16* w_ocf1  = prep(in[21], 128, 64);
  u16* w_ocl1  = prep(in[23],  64, 64);
  u16* w_com1  = prep(in[25],  64, 216);
  u16* w_em11  = prep(in[27], 128, 64);
  u16* w_em21  = prep(in[29],  64, 72);
  u16* w_ocf2  = prep(in[33], 128, 64);
  u16* w_ocl2  = prep(in[35],  64, 64);
  u16* w_com2  = prep(in[37],  64, 216);
  u16* w_em12  = prep(in[39], 128, 64);
  u16* w_em22  = prep(in[41],  64, 72);
  u16* w_occ0  = prep(in[45], 128, 64);
  u16* w_fcc0  = prep(in[47], 128, 64);
  u16* w_occ1  = prep(in[49], 128, 64);
  u16* w_fcc1  = prep(in[51], 128, 64);
  u16* w_cas1  = prep(in[53], 128, 64);
  u16* w_cas2  = prep(in[55],  64, 64);
  u16* w_casc  = prep(in[57],  64, 216);

  // ----- level 2 (48x48) -----
  const int h2 = 48;
  conv3(stream, nrf2, 64, rf2, 64,  w_ocf2, in[34], A,   64,  h2, h2, 1);
  conv3(stream, A,    64, 0,   0,   w_ocl2, in[36], of2, 64,  h2, h2, 1);
  conv3(stream, swf2, 64, 0,   0,   w_com2, in[38], OM,  216, h2, h2, 0);
  conv3(stream, of2,  64, swf2, 64, w_em12, in[40], Bb,  64,  h2, h2, 1);
  conv3(stream, Bb,   64, 0,   0,   w_em22, in[42], EM,  72,  h2, h2, 2);
  dconv(stream, of2,  OM, EM,  72, 0,   in[43], in[44], sh2, h2, h2, 0, 0);
  dconv(stream, nrf2, OM, OM, 216, 144, in[43], in[44], dn2, h2, h2, 1, 1);

  // ----- level 1 (96x96) -----
  const int h1 = 96;
  up2(stream, of2, U, h2, h2);
  conv3(stream, nrf1, 64, rf1, 64,  w_ocf1, in[22], A,   64,  h1, h1, 1);
  conv3(stream, A,    64, U,   64,  w_occ1, in[50], Bb,  64,  h1, h1, 1);
  conv3(stream, Bb,   64, 0,   0,   w_ocl1, in[24], of1, 64,  h1, h1, 1);
  conv3(stream, swf1, 64, 0,   0,   w_com1, in[26], OM,  216, h1, h1, 0);
  conv3(stream, of1,  64, swf1, 64, w_em11, in[28], A,   64,  h1, h1, 1);
  conv3(stream, A,    64, 0,   0,   w_em21, in[30], EM,  72,  h1, h1, 2);
  dconv(stream, of1,  OM, EM,  72, 0,   in[31], in[32], sh1, h1, h1, 0, 0);
  dconv(stream, nrf1, OM, OM, 216, 144, in[31], in[32], A,   h1, h1, 1, 0);
  up2(stream, dn2, U, h2, h2);
  conv3(stream, A,    64, U,   64,  w_fcc1, in[52], dn1, 64,  h1, h1, 1);

  // ----- level 0 (192x192) -----
  const int h0 = 192;
  up2(stream, of1, U, h1, h1);
  conv3(stream, nrf0, 64, rf0, 64,  w_ocf0, in[10], A,   64,  h0, h0, 1);
  conv3(stream, A,    64, U,   64,  w_occ0, in[46], Bb,  64,  h0, h0, 1);
  conv3(stream, Bb,   64, 0,   0,   w_ocl0, in[12], A,   64,  h0, h0, 1);
  conv3(stream, swf0, 64, 0,   0,   w_com0, in[14], OM,  216, h0, h0, 0);
  conv3(stream, A,    64, swf0, 64, w_em10, in[16], Bb,  64,  h0, h0, 1);
  conv3(stream, Bb,   64, 0,   0,   w_em20, in[18], EM,  72,  h0, h0, 2);
  dconv(stream, A,    OM, EM,  72, 0,   in[19], in[20], sh0, h0, h0, 0, 0);
  dconv(stream, nrf0, OM, OM, 216, 144, in[19], in[20], Bb,  h0, h0, 1, 0);
  up2(stream, dn1, U, h1, h1);
  conv3(stream, Bb,   64, U,   64,  w_fcc0, in[48], A,   64,  h0, h0, 0);
  conv3(stream, A,    64, rf0, 64,  w_cas1, in[54], Bb,  64,  h0, h0, 1);
  conv3(stream, Bb,   64, 0,   0,   w_cas2, in[56], U,   64,  h0, h0, 1);
  conv3(stream, U,    64, 0,   0,   w_casc, in[58], OM,  216, h0, h0, 0);
  dconv(stream, A,    OM, OM, 216, 144, in[59], in[60], out0, h0, h0, 1, 1);
}